// Round 1
// baseline (91.585 us; speedup 1.0000x reference)
//
#include <hip/hip_runtime.h>

// Problem constants (fixed by setup_inputs)
#define K  19
#define C  256
#define HF 64
#define WF 128
#define BB 4
#define HL 512
#define WL 1024

// One thread per low-res pixel. Computes argmin_k ||f - c_k||^2 (== argmin of
// c2_k - 2*dot_k, since f2 is constant over k) with f64 accumulation to match
// the exact argmin, then writes the 8x8 nearest-upsampled block directly.
__global__ __launch_bounds__(256) void centroid_mask_kernel(
    const float* __restrict__ feat0,   // feature_s2t
    const float* __restrict__ feat1,   // feature_target
    const float* __restrict__ cent0,   // centroid used for map 0 (centroid_target)
    const float* __restrict__ cent1,   // centroid used for map 1 (centroid_s2t)
    int* __restrict__ out)             // [2][BB][HL][WL] int32
{
    __shared__ double sc[K * C];   // centroids as f64, [k][c]
    __shared__ double sc2[K];      // ||c_k||^2

    const int map = blockIdx.y;
    const float* __restrict__ feat = (map == 0) ? feat0 : feat1;
    const float* __restrict__ cent = (map == 0) ? cent0 : cent1;

    const int tid = threadIdx.x;

    // Stage centroids into LDS as f64 (f32->f64 is exact)
    for (int i = tid; i < K * C; i += 256)
        sc[i] = (double)cent[i];
    __syncthreads();
    if (tid < K) {
        double s = 0.0;
        for (int c = 0; c < C; ++c) {
            double v = sc[tid * C + c];
            s += v * v;
        }
        sc2[tid] = s;
    }
    __syncthreads();

    const int p = blockIdx.x * 256 + tid;   // 0 .. 32767
    const int w = p & (WF - 1);             // lane-consecutive -> coalesced
    const int h = (p >> 7) & (HF - 1);
    const int b = p >> 13;

    double acc[K];
    #pragma unroll
    for (int k = 0; k < K; ++k) acc[k] = 0.0;

    // feature [B][C][HF][WF]: channel stride = HF*WF
    const float* __restrict__ fp = feat + (size_t)b * C * HF * WF + (size_t)h * WF + w;
    #pragma unroll 4
    for (int c = 0; c < C; ++c) {
        double f = (double)fp[(size_t)c * (HF * WF)];
        #pragma unroll
        for (int k = 0; k < K; ++k)
            acc[k] += f * sc[k * C + c];   // wave-uniform LDS read (broadcast)
    }

    // argmin with strict < : first minimum, matching jnp.argmin tie-break
    int best = 0;
    double bestd = sc2[0] - 2.0 * acc[0];
    #pragma unroll
    for (int k = 1; k < K; ++k) {
        double d = sc2[k] - 2.0 * acc[k];
        if (d < bestd) { bestd = d; best = k; }
    }

    // Nearest-upsample 8x8: out[map][b][h*8+r][w*8 + 0..7] = best
    int4 v = make_int4(best, best, best, best);
    int* __restrict__ ob = out + (size_t)map * (BB * HL * WL)
                               + (size_t)b * (HL * WL)
                               + (size_t)(h * 8) * WL + (size_t)(w * 8);
    #pragma unroll
    for (int r = 0; r < 8; ++r) {
        *(int4*)(ob + (size_t)r * WL)     = v;   // lane i -> 32 contiguous bytes
        *(int4*)(ob + (size_t)r * WL + 4) = v;   // wave -> 2KB contiguous per row
    }
}

extern "C" void kernel_launch(void* const* d_in, const int* in_sizes, int n_in,
                              void* d_out, int out_size, void* d_ws, size_t ws_size,
                              hipStream_t stream) {
    const float* feature_s2t     = (const float*)d_in[0];
    const float* feature_target  = (const float*)d_in[1];
    // d_in[2], d_in[3]: labels — only their shapes matter, unused here
    const float* centroid_s2t    = (const float*)d_in[4];
    const float* centroid_target = (const float*)d_in[5];
    int* out = (int*)d_out;

    // map 0: feature_s2t vs centroid_target; map 1: feature_target vs centroid_s2t
    dim3 grid(32768 / 256, 2);
    dim3 block(256);
    hipLaunchKernelGGL(centroid_mask_kernel, grid, block, 0, stream,
                       feature_s2t, feature_target,
                       centroid_target, centroid_s2t, out);
}

// Round 2
// 79.199 us; speedup vs baseline: 1.1564x; 1.1564x over previous
//
#include <hip/hip_runtime.h>

// Problem constants (fixed by setup_inputs)
#define K    19
#define C    256
#define HF   64
#define WF   128
#define HW   (HF * WF)
#define BB   4
#define HL   512
#define WL   1024

#define SUBS 8            // lanes per pixel (channel split)
#define CPS  (C / SUBS)   // 32 channels per sub-lane
#define PADW 33           // padded inner dim: sub stride 33 doubles -> distinct banks
#define PIX_PER_BLOCK 32  // 256 threads / 8 subs

// 8 lanes per low-res pixel: lane = sub*8 + pix. Each lane accumulates a 32-channel
// f64 partial dot against all 19 centroids (LDS f64, bank-conflict-free padded
// layout), butterfly-reduces across subs, computes the exact argmin of
// ||c_k||^2 - 2*dot_k, and writes one row of the pixel's 8x8 upsampled block.
__global__ __launch_bounds__(256) void centroid_mask_kernel(
    const float* __restrict__ feat0,   // feature_s2t
    const float* __restrict__ feat1,   // feature_target
    const float* __restrict__ cent0,   // centroids for map 0 (centroid_target)
    const float* __restrict__ cent1,   // centroids for map 1 (centroid_s2t)
    int* __restrict__ out)             // [2][BB][HL][WL] int32
{
    __shared__ double sc[K * SUBS * PADW];   // [k][sub][33] f64 = 40128 B
    __shared__ double sc2p[K * SUBS];        // per-(k,sub) partial ||c||^2
    __shared__ double sc2[K];                // ||c_k||^2

    const int map = blockIdx.y;
    const float* __restrict__ feat = (map == 0) ? feat0 : feat1;
    const float* __restrict__ cent = (map == 0) ? cent0 : cent1;

    const int tid = threadIdx.x;

    // Stage centroids into LDS as f64 (f32->f64 exact), padded layout
    for (int idx = tid; idx < K * C; idx += 256) {
        int k = idx >> 8;        // idx / 256
        int c = idx & (C - 1);   // idx % 256
        sc[k * (SUBS * PADW) + (c >> 5) * PADW + (c & 31)] = (double)cent[idx];
    }
    __syncthreads();

    // ||c_k||^2: parallel partials over (k, sub), then 8-way sum
    if (tid < K * SUBS) {
        const double* p = &sc[(tid >> 3) * (SUBS * PADW) + (tid & 7) * PADW];
        double s = 0.0;
        #pragma unroll
        for (int i = 0; i < CPS; ++i) s += p[i] * p[i];
        sc2p[tid] = s;
    }
    __syncthreads();
    if (tid < K) {
        double s = 0.0;
        #pragma unroll
        for (int j = 0; j < SUBS; ++j) s += sc2p[tid * SUBS + j];
        sc2[tid] = s;
    }
    __syncthreads();

    const int lane = tid & 63;
    const int wv   = tid >> 6;        // wave in block: 0..3
    const int sub  = lane >> 3;       // 0..7: channel quarter-of-quarter
    const int pix  = lane & 7;        // 0..7: consecutive pixels in w

    const int p = blockIdx.x * PIX_PER_BLOCK + wv * 8 + pix;   // 0..32767
    const int w = p & (WF - 1);
    const int h = (p >> 7) & (HF - 1);
    const int b = p >> 13;

    double acc[K];
    #pragma unroll
    for (int k = 0; k < K; ++k) acc[k] = 0.0;

    // feature [B][C][HF][WF]; this lane covers channels [sub*32, sub*32+32)
    const float*  __restrict__ fp = feat + (size_t)b * C * HW
                                         + (size_t)(sub * CPS) * HW
                                         + (size_t)h * WF + w;
    const double* __restrict__ cp = &sc[sub * PADW];   // + k*(SUBS*PADW) + i

    #pragma unroll 4
    for (int i = 0; i < CPS; ++i) {
        double f = (double)fp[(size_t)i * HW];
        #pragma unroll
        for (int k = 0; k < K; ++k)
            acc[k] = fma(f, cp[k * (SUBS * PADW) + i], acc[k]);
    }

    // Reduce partial dots across the 8 subs (lane bits 3..5)
    #pragma unroll
    for (int k = 0; k < K; ++k) {
        double a = acc[k];
        a += __shfl_xor(a, 8, 64);
        a += __shfl_xor(a, 16, 64);
        a += __shfl_xor(a, 32, 64);
        acc[k] = a;
    }

    // argmin with strict < (first minimum, matching jnp/np tie-break)
    int best = 0;
    double bestd = sc2[0] - 2.0 * acc[0];
    #pragma unroll
    for (int k = 1; k < K; ++k) {
        double d = sc2[k] - 2.0 * acc[k];
        if (d < bestd) { bestd = d; best = k; }
    }

    // Each lane writes one row (row = sub) of the pixel's 8x8 upsampled block
    int4 v = make_int4(best, best, best, best);
    int* __restrict__ ob = out + (size_t)map * (BB * HL * WL)
                               + (size_t)b * (HL * WL)
                               + (size_t)(h * 8 + sub) * WL + (size_t)(w * 8);
    *(int4*)(ob)     = v;
    *(int4*)(ob + 4) = v;
}

extern "C" void kernel_launch(void* const* d_in, const int* in_sizes, int n_in,
                              void* d_out, int out_size, void* d_ws, size_t ws_size,
                              hipStream_t stream) {
    const float* feature_s2t     = (const float*)d_in[0];
    const float* feature_target  = (const float*)d_in[1];
    // d_in[2], d_in[3]: labels — only shapes matter, unused
    const float* centroid_s2t    = (const float*)d_in[4];
    const float* centroid_target = (const float*)d_in[5];
    int* out = (int*)d_out;

    dim3 grid(32768 / PIX_PER_BLOCK, 2);   // (1024, 2)
    dim3 block(256);
    hipLaunchKernelGGL(centroid_mask_kernel, grid, block, 0, stream,
                       feature_s2t, feature_target,
                       centroid_target, centroid_s2t, out);
}

// Round 3
// 56.986 us; speedup vs baseline: 1.6072x; 1.3898x over previous
//
#include <hip/hip_runtime.h>

// Problem constants (fixed by setup_inputs)
#define K   19
#define C   256
#define HF  64
#define WF  128
#define HW  (HF * WF)
#define BB  4
#define HL  512
#define WL  1024

// f32 near-tie threshold: our f32 d-error bound is ~2.2e-3; TAU > 2*err + margin.
// Pixels whose top-2 f32 gap < TAU get an exact f64 recompute of the candidates.
#define TAU 0.015f

// Block = 256 threads = 4 waves; wave wv covers channels [wv*64, wv*64+64) for
// 64 pixels (lane = pixel). Centroid reads are wave-uniform -> scalar loads ->
// the inner loop is pure v_fma_f32 (SGPR centroid operand, VGPR feature/acc).
__global__ __launch_bounds__(256) void centroid_mask_kernel(
    const float* __restrict__ feat0,   // feature_s2t
    const float* __restrict__ feat1,   // feature_target
    const float* __restrict__ cent0,   // centroids for map 0 (centroid_target)
    const float* __restrict__ cent1,   // centroids for map 1 (centroid_s2t)
    int* __restrict__ out)             // [2][BB][HL][WL] int32
{
    __shared__ float  part[4][64][20];   // per-wave partial dots [wv][pix][k]
    __shared__ double c2p[K][8];         // exact ||c||^2 partials
    __shared__ double sc2d[K];           // exact ||c||^2 (f64)
    __shared__ float  sc2f[K];           // rounded-exact ||c||^2 (f32)

    const int map = blockIdx.y;
    const float* __restrict__ feat = (map == 0) ? feat0 : feat1;
    const float* __restrict__ cent = (map == 0) ? cent0 : cent1;

    const int tid  = threadIdx.x;
    const int lane = tid & 63;
    const int wv   = __builtin_amdgcn_readfirstlane(tid >> 6);   // wave-uniform

    // ---- exact ||c_k||^2 partials (f64), 152 threads ----
    if (tid < K * 8) {
        const int k = tid >> 3, sl = tid & 7;
        const float* cp = cent + k * C + sl * 32;
        double s = 0.0;
        #pragma unroll
        for (int j = 0; j < 32; ++j) { double v = (double)cp[j]; s = fma(v, v, s); }
        c2p[k][sl] = s;
    }

    // ---- main: preload this wave's 64 feature channels for pixel=lane ----
    const int p  = blockIdx.x * 64 + lane;     // pixel in [0, 32768)
    const int hw = p & (HW - 1);
    const int b  = p >> 13;
    const int cbase = wv * 64;

    const float* __restrict__ fp = feat + (size_t)b * C * HW + (size_t)cbase * HW + hw;
    float f[64];
    #pragma unroll
    for (int i = 0; i < 64; ++i) f[i] = fp[(size_t)i * HW];

    // 19 x 64 FMAs, centroid operand wave-uniform (scalar-load eligible)
    for (int k = 0; k < K; ++k) {
        const float4* __restrict__ c4 = (const float4*)(cent + (size_t)k * C + cbase);
        float a0 = 0.f, a1 = 0.f, a2 = 0.f, a3 = 0.f;
        #pragma unroll
        for (int j = 0; j < 16; ++j) {
            float4 cc = c4[j];
            a0 = fmaf(f[4*j+0], cc.x, a0);
            a1 = fmaf(f[4*j+1], cc.y, a1);
            a2 = fmaf(f[4*j+2], cc.z, a2);
            a3 = fmaf(f[4*j+3], cc.w, a3);
        }
        part[wv][lane][k] = (a0 + a1) + (a2 + a3);
    }
    __syncthreads();

    if (tid < K) {
        double s = 0.0;
        #pragma unroll
        for (int j = 0; j < 8; ++j) s += c2p[tid][j];
        sc2d[tid] = s;
        sc2f[tid] = (float)s;
    }
    __syncthreads();

    // ---- epilogue: wave 0, lane = pixel ----
    if (tid < 64) {
        const int pix = tid;
        float d[K];
        #pragma unroll
        for (int k = 0; k < K; ++k) {
            float s = (part[0][pix][k] + part[1][pix][k])
                    + (part[2][pix][k] + part[3][pix][k]);
            d[k] = sc2f[k] - 2.0f * s;
        }
        int best = 0; float m1 = d[0];
        #pragma unroll
        for (int k = 1; k < K; ++k) if (d[k] < m1) { m1 = d[k]; best = k; }

        // candidate mask: everything within TAU of the f32 min (includes best)
        unsigned cmask = 0u;
        #pragma unroll
        for (int k = 0; k < K; ++k) if (d[k] - m1 < TAU) cmask |= (1u << k);

        if (cmask & (cmask - 1)) {   // near-tie: exact f64 recompute of candidates
            const float* __restrict__ fcol = feat + (size_t)b * C * HW + hw;
            double bd = 1e300; int bi = 0;
            for (int k = 0; k < K; ++k) {
                if ((cmask >> k) & 1) {
                    const float* __restrict__ ck = cent + (size_t)k * C;
                    double s = 0.0;
                    for (int c = 0; c < C; ++c)
                        s = fma((double)fcol[(size_t)c * HW], (double)ck[c], s);
                    double dk = sc2d[k] - 2.0 * s;
                    if (dk < bd) { bd = dk; bi = k; }   // strict <, ascending k
                }
            }
            best = bi;
        }

        // write the 8x8 nearest-upsampled block
        const int w = hw & (WF - 1);
        const int h = hw >> 7;
        int4 v = make_int4(best, best, best, best);
        int* __restrict__ ob = out + (size_t)map * (BB * HL * WL)
                                   + (size_t)b * (HL * WL)
                                   + (size_t)(h * 8) * WL + (size_t)(w * 8);
        #pragma unroll
        for (int r = 0; r < 8; ++r) {
            *(int4*)(ob + (size_t)r * WL)     = v;
            *(int4*)(ob + (size_t)r * WL + 4) = v;
        }
    }
}

extern "C" void kernel_launch(void* const* d_in, const int* in_sizes, int n_in,
                              void* d_out, int out_size, void* d_ws, size_t ws_size,
                              hipStream_t stream) {
    const float* feature_s2t     = (const float*)d_in[0];
    const float* feature_target  = (const float*)d_in[1];
    // d_in[2], d_in[3]: labels — only shapes matter, unused
    const float* centroid_s2t    = (const float*)d_in[4];
    const float* centroid_target = (const float*)d_in[5];
    int* out = (int*)d_out;

    dim3 grid(32768 / 64, 2);   // (512, 2)
    dim3 block(256);
    hipLaunchKernelGGL(centroid_mask_kernel, grid, block, 0, stream,
                       feature_s2t, feature_target,
                       centroid_target, centroid_s2t, out);
}

// Round 4
// 43.244 us; speedup vs baseline: 2.1179x; 1.3178x over previous
//
#include <hip/hip_runtime.h>

// Problem constants (fixed by setup_inputs)
#define K   19
#define C   256
#define HF  64
#define WF  128
#define HW  (HF * WF)
#define BB  4
#define HL  512
#define WL  1024

// f32 near-tie threshold: f32 distance error bound here is < ~1e-3;
// pixels whose top-2 f32 gap < TAU get an exact f64 recompute (rare).
#define TAU 0.015f

// Block = 512 threads = 8 waves, 64 pixels (lane = pixel). Wave wv covers
// channels [wv*32, wv*32+32). Centroid reads are wave-uniform (scalar-load
// eligible); features preload to 32 VGPRs; partial dots meet in LDS with a
// lane-contiguous [wv][k][pix] layout (conflict-free). Built for <=64 VGPR
// so 4 blocks (32 waves) co-reside per CU.
__global__ __launch_bounds__(512, 8) void centroid_mask_kernel(
    const float* __restrict__ feat0,   // feature_s2t
    const float* __restrict__ feat1,   // feature_target
    const float* __restrict__ cent0,   // centroids for map 0 (centroid_target)
    const float* __restrict__ cent1,   // centroids for map 1 (centroid_s2t)
    int* __restrict__ out)             // [2][BB][HL][WL] int32
{
    __shared__ float  part[8 * K * 64];  // [wv][k][pix], pix stride 1 -> no conflicts
    __shared__ double c2p[K][8];         // exact ||c||^2 partials
    __shared__ double sc2d[K];           // exact ||c||^2 (f64)
    __shared__ float  sc2f[K];           // rounded-exact ||c||^2 (f32)

    const int map = blockIdx.y;
    const float* __restrict__ feat = (map == 0) ? feat0 : feat1;
    const float* __restrict__ cent = (map == 0) ? cent0 : cent1;

    const int tid  = threadIdx.x;
    const int lane = tid & 63;
    const int wv   = __builtin_amdgcn_readfirstlane(tid >> 6);   // 0..7, uniform

    // ---- exact ||c_k||^2 partials (f64), 152 threads, overlaps with main ----
    if (tid < K * 8) {
        const int k = tid >> 3, sl = tid & 7;
        const float* cp = cent + k * C + sl * 32;
        double s = 0.0;
        #pragma unroll
        for (int j = 0; j < 32; ++j) { double v = (double)cp[j]; s = fma(v, v, s); }
        c2p[k][sl] = s;
    }

    // ---- main: this wave's 32 feature channels for pixel = lane ----
    const int p  = blockIdx.x * 64 + lane;     // pixel in [0, 32768)
    const int hw = p & (HW - 1);
    const int b  = p >> 13;
    const int cbase = wv * 32;

    const float* __restrict__ fp = feat + (size_t)b * C * HW + (size_t)cbase * HW + hw;
    float f[32];
    #pragma unroll
    for (int i = 0; i < 32; ++i) f[i] = fp[(size_t)i * HW];

    // 19 x 32 FMAs; centroid operand wave-uniform. 4-way split accumulators.
    float* __restrict__ pw = &part[(wv * K) * 64 + lane];
    #pragma unroll
    for (int k = 0; k < K; ++k) {
        const float* __restrict__ ck = cent + (size_t)k * C + cbase;
        float a0 = 0.f, a1 = 0.f, a2 = 0.f, a3 = 0.f;
        #pragma unroll
        for (int j = 0; j < 8; ++j) {
            a0 = fmaf(f[4*j+0], ck[4*j+0], a0);
            a1 = fmaf(f[4*j+1], ck[4*j+1], a1);
            a2 = fmaf(f[4*j+2], ck[4*j+2], a2);
            a3 = fmaf(f[4*j+3], ck[4*j+3], a3);
        }
        pw[k * 64] = (a0 + a1) + (a2 + a3);   // ds_write_b32, lane-contiguous
    }
    __syncthreads();

    if (tid < K) {
        double s = 0.0;
        #pragma unroll
        for (int j = 0; j < 8; ++j) s += c2p[tid][j];
        sc2d[tid] = s;
        sc2f[tid] = (float)s;
    }
    __syncthreads();

    // ---- epilogue: wave 0, lane = pixel ----
    if (tid < 64) {
        const int pix = tid;
        float d[K];
        #pragma unroll
        for (int k = 0; k < K; ++k) {
            float s = 0.f;
            #pragma unroll
            for (int w8 = 0; w8 < 8; ++w8)
                s += part[(w8 * K + k) * 64 + pix];
            d[k] = sc2f[k] - 2.0f * s;
        }
        int best = 0; float m1 = d[0];
        #pragma unroll
        for (int k = 1; k < K; ++k) if (d[k] < m1) { m1 = d[k]; best = k; }

        // near-tie candidates within TAU of the f32 min
        unsigned cmask = 0u;
        #pragma unroll
        for (int k = 0; k < K; ++k) if (d[k] - m1 < TAU) cmask |= (1u << k);

        if (cmask & (cmask - 1)) {   // rare: exact f64 recompute of candidates
            const float* __restrict__ fcol = feat + (size_t)b * C * HW + hw;
            double bd = 1e300; int bi = 0;
            for (int k = 0; k < K; ++k) {
                if ((cmask >> k) & 1) {
                    const float* __restrict__ ck = cent + (size_t)k * C;
                    double s = 0.0;
                    for (int c = 0; c < C; ++c)
                        s = fma((double)fcol[(size_t)c * HW], (double)ck[c], s);
                    double dk = sc2d[k] - 2.0 * s;
                    if (dk < bd) { bd = dk; bi = k; }   // strict <, ascending k
                }
            }
            best = bi;
        }

        // write the 8x8 nearest-upsampled block
        const int w = hw & (WF - 1);
        const int h = hw >> 7;
        int4 v = make_int4(best, best, best, best);
        int* __restrict__ ob = out + (size_t)map * (BB * HL * WL)
                                   + (size_t)b * (HL * WL)
                                   + (size_t)(h * 8) * WL + (size_t)(w * 8);
        #pragma unroll
        for (int r = 0; r < 8; ++r) {
            *(int4*)(ob + (size_t)r * WL)     = v;
            *(int4*)(ob + (size_t)r * WL + 4) = v;
        }
    }
}

extern "C" void kernel_launch(void* const* d_in, const int* in_sizes, int n_in,
                              void* d_out, int out_size, void* d_ws, size_t ws_size,
                              hipStream_t stream) {
    const float* feature_s2t     = (const float*)d_in[0];
    const float* feature_target  = (const float*)d_in[1];
    // d_in[2], d_in[3]: labels — only shapes matter, unused
    const float* centroid_s2t    = (const float*)d_in[4];
    const float* centroid_target = (const float*)d_in[5];
    int* out = (int*)d_out;

    dim3 grid(32768 / 64, 2);   // (512, 2) -> 1024 blocks, 4/CU, 32 waves/CU
    dim3 block(512);
    hipLaunchKernelGGL(centroid_mask_kernel, grid, block, 0, stream,
                       feature_s2t, feature_target,
                       centroid_target, centroid_s2t, out);
}